// Round 1
// baseline (645.942 us; speedup 1.0000x reference)
//
#include <hip/hip_runtime.h>

#define NA 32
#define HID 128
#define NH 8
#define HD 16

__global__ __launch_bounds__(256) void soft_attn_kernel(
    const float* __restrict__ h, const float* __restrict__ msg,
    const float* __restrict__ mask,
    const float* __restrict__ qW, const float* __restrict__ qb,
    const float* __restrict__ kW, const float* __restrict__ kb,
    const float* __restrict__ vW, const float* __restrict__ vb,
    const float* __restrict__ dW, const float* __restrict__ db,
    const float* __restrict__ lnw, const float* __restrict__ lnb,
    float* __restrict__ out)
{
  const int tok = blockIdx.x;   // 0..16383  (b*1024 + n)
  const int t = threadIdx.x;    // 0..255

  __shared__ __align__(16) float s_msg[NA * HID];  // 16 KB
  __shared__ __align__(16) float s_k[NA * 129];    // padded: stride 129 kills bank conflicts
  __shared__ __align__(16) float s_v[NA * 129];
  __shared__ __align__(16) float s_h[HID];
  __shared__ __align__(16) float s_q[HID];
  __shared__ __align__(16) float s_ctx[HID];
  __shared__ __align__(16) float s_p[NH * NA];
  __shared__ __align__(16) float s_x[HID];
  __shared__ float s_red[2];

  // ---- stage message tile + h into LDS (coalesced float4) ----
  {
    const float4* src = (const float4*)(msg + (size_t)tok * NA * HID);
    float4* dst = (float4*)s_msg;
#pragma unroll
    for (int j = 0; j < 4; ++j) dst[t + j * 256] = src[t + j * 256];
  }
  if (t < 32) ((float4*)s_h)[t] = ((const float4*)(h + (size_t)tok * HID))[t];
  __syncthreads();

  // ---- q projection: q[o] = sum_i h[i]*qW[i][o] + qb[o]  (threads 0..127) ----
  if (t < HID) {
    float acc = qb[t];
#pragma unroll 4
    for (int i = 0; i < HID; ++i) acc = fmaf(s_h[i], qW[i * HID + t], acc);
    s_q[t] = acc;
  }

  // ---- k/v projections: thread handles 4 a's x 4 o's ----
  {
    const int o4 = (t & 31) * 4;   // output col base (0..124)
    const int a0 = (t >> 5) * 4;   // message row base (0..28)
    const float4 kbv = *(const float4*)(kb + o4);
    const float4 vbv = *(const float4*)(vb + o4);
    float ka[4][4], va[4][4];
#pragma unroll
    for (int j = 0; j < 4; ++j) {
      ka[j][0] = kbv.x; ka[j][1] = kbv.y; ka[j][2] = kbv.z; ka[j][3] = kbv.w;
      va[j][0] = vbv.x; va[j][1] = vbv.y; va[j][2] = vbv.z; va[j][3] = vbv.w;
    }
#pragma unroll 2
    for (int i = 0; i < HID; ++i) {
      const float4 kw = *(const float4*)(kW + i * HID + o4);  // coalesced, L2-hot
      const float4 vw = *(const float4*)(vW + i * HID + o4);
#pragma unroll
      for (int j = 0; j < 4; ++j) {
        const float m = s_msg[(a0 + j) * HID + i];  // 2-addr broadcast (free)
        ka[j][0] = fmaf(m, kw.x, ka[j][0]);
        ka[j][1] = fmaf(m, kw.y, ka[j][1]);
        ka[j][2] = fmaf(m, kw.z, ka[j][2]);
        ka[j][3] = fmaf(m, kw.w, ka[j][3]);
        va[j][0] = fmaf(m, vw.x, va[j][0]);
        va[j][1] = fmaf(m, vw.y, va[j][1]);
        va[j][2] = fmaf(m, vw.z, va[j][2]);
        va[j][3] = fmaf(m, vw.w, va[j][3]);
      }
    }
#pragma unroll
    for (int j = 0; j < 4; ++j) {
      const int a = a0 + j;
#pragma unroll
      for (int oo = 0; oo < 4; ++oo) {
        s_k[a * 129 + o4 + oo] = ka[j][oo];
        s_v[a * 129 + o4 + oo] = fmaxf(va[j][oo], 0.f);  // relu
      }
    }
  }
  __syncthreads();

  // ---- scores + masked softmax: thread (head = t>>5, a = t&31) ----
  {
    const int head = t >> 5;
    const int a = t & 31;
    float sc = 0.f;
#pragma unroll
    for (int d = 0; d < HD; ++d)
      sc = fmaf(s_q[head * HD + d], s_k[a * 129 + head * HD + d], sc);
    const float m = mask[(size_t)tok * NA + a];
    sc = sc * 0.25f * m;                 // /sqrt(16) * mask
    if (sc == 0.0f) sc = -1000000.0f;    // exact reference semantics
    float mx = sc;
#pragma unroll
    for (int off = 16; off; off >>= 1) mx = fmaxf(mx, __shfl_xor(mx, off));
    const float e = __expf(sc - mx);
    float sm = e;
#pragma unroll
    for (int off = 16; off; off >>= 1) sm += __shfl_xor(sm, off);
    s_p[head * NA + a] = e / sm * m;     // softmax * mask
  }
  __syncthreads();

  // ---- PV: ctx[o] = sum_a p[head(o)][a] * v[a][o]  (threads 0..127) ----
  if (t < HID) {
    const int head = t >> 4;
    float acc = 0.f;
#pragma unroll
    for (int a = 0; a < NA; ++a)
      acc = fmaf(s_p[head * NA + a], s_v[a * 129 + t], acc);
    s_ctx[t] = acc;
  }
  __syncthreads();

  // ---- output projection + residual ----
  if (t < HID) {
    float acc = db[t];
#pragma unroll 4
    for (int i = 0; i < HID; ++i) acc = fmaf(s_ctx[i], dW[i * HID + t], acc);
    s_x[t] = acc + s_h[t];
  }
  __syncthreads();

  // ---- layernorm over 128 (one wave reduces two halves) ----
  if (t < 64) {
    const float x0 = s_x[t], x1 = s_x[t + 64];
    float s1 = x0 + x1;
    float s2 = x0 * x0 + x1 * x1;
#pragma unroll
    for (int off = 32; off; off >>= 1) {
      s1 += __shfl_xor(s1, off);
      s2 += __shfl_xor(s2, off);
    }
    if (t == 0) {
      const float u = s1 * (1.f / 128.f);
      const float var = s2 * (1.f / 128.f) - u * u;
      s_red[0] = u;
      s_red[1] = rsqrtf(var + 1e-12f);
    }
  }
  __syncthreads();
  if (t < HID) {
    const float y = lnw[t] * ((s_x[t] - s_red[0]) * s_red[1]) + lnb[t];
    out[(size_t)tok * HID + t] = y;
  }
}

extern "C" void kernel_launch(void* const* d_in, const int* in_sizes, int n_in,
                              void* d_out, int out_size, void* d_ws, size_t ws_size,
                              hipStream_t stream) {
  const float* h    = (const float*)d_in[0];
  const float* msg  = (const float*)d_in[1];
  const float* mask = (const float*)d_in[2];
  const float* qW   = (const float*)d_in[3];
  const float* qb   = (const float*)d_in[4];
  const float* kW   = (const float*)d_in[5];
  const float* kb   = (const float*)d_in[6];
  const float* vW   = (const float*)d_in[7];
  const float* vb   = (const float*)d_in[8];
  const float* dW   = (const float*)d_in[9];
  const float* db   = (const float*)d_in[10];
  const float* lnw  = (const float*)d_in[11];
  const float* lnb  = (const float*)d_in[12];
  float* out = (float*)d_out;

  const int n_tokens = in_sizes[0] / HID;  // 16*1024 = 16384
  soft_attn_kernel<<<n_tokens, 256, 0, stream>>>(
      h, msg, mask, qW, qb, kW, kb, vW, vb, dW, db, lnw, lnb, out);
}

// Round 2
// 124.237 us; speedup vs baseline: 5.1993x; 5.1993x over previous
//
#include <hip/hip_runtime.h>

typedef short  short4v  __attribute__((ext_vector_type(4)));
typedef float  float4v  __attribute__((ext_vector_type(4)));

#define NA   32
#define HID  128
#define NH   8
#define TPB  8      // tokens per block
#define KSTR 132    // padded fp32 row stride for s_k/s_v

__device__ __forceinline__ unsigned short f2bf(float f) {
  unsigned int u = __float_as_uint(f);
  return (unsigned short)((u + 0x7FFFu + ((u >> 16) & 1u)) >> 16);  // RNE
}

__global__ __launch_bounds__(256, 2) void soft_attn_mfma(
    const float* __restrict__ h, const float* __restrict__ msg,
    const float* __restrict__ mask,
    const float* __restrict__ qW, const float* __restrict__ qb,
    const float* __restrict__ kW, const float* __restrict__ kb,
    const float* __restrict__ vW, const float* __restrict__ vb,
    const float* __restrict__ dW, const float* __restrict__ db,
    const float* __restrict__ lnw, const float* __restrict__ lnb,
    float* __restrict__ out, int n_tokens)
{
  const int t    = threadIdx.x;
  const int lane = t & 63;
  const int w    = t >> 6;        // wave id, owns output cols [w*32, w*32+32)
  const int n0   = w * 32;
  const int lm   = lane & 15;     // m (or n) index within a 16-tile
  const int lg   = lane >> 4;     // k-group (0..3)
  const int tok0 = blockIdx.x * TPB;
  if (tok0 >= n_tokens) return;

  // fragment-order bf16 buffers: frag f occupies [f*64 + lane] short4 slots
  __shared__ __align__(16) short s_msgF[16 * 64 * 4];  // 8 KB : message A-frags (2 mt x 8 ks)
  __shared__ __align__(16) short s_hF  [ 8 * 64 * 4];  // 4 KB : h A-frags (rows = tokens)
  __shared__ __align__(16) short s_ctxF[ 8 * 64 * 4];  // 4 KB : ctx A-frags (rows = tokens)
  __shared__ __align__(16) float s_qall[TPB * HID];    // 4 KB : q per token (fp32)
  __shared__ __align__(16) float s_hall[TPB * HID];    // 4 KB : h per token (fp32, residual)
  __shared__ __align__(16) float s_dall[TPB * HID];    // 4 KB : d-proj outputs
  __shared__ __align__(16) float s_k[NA * KSTR];       // 16.9 KB
  __shared__ __align__(16) float s_v[NA * KSTR];       // 16.9 KB
  __shared__ __align__(16) float s_p[NH * NA];         // 1 KB

  // ---- stage h: fp32 rows + bf16 frags; zero ctxF pad rows (m>=TPB) ----
  {
    ((float4v*)s_hall)[t] = ((const float4v*)(h + (size_t)tok0 * HID))[t];
#pragma unroll
    for (int j = 0; j < 2; ++j) {
      const int s  = t + 256 * j;        // slot id: 8 frags x 64 lanes
      const int f  = s >> 6;
      const int sl = s & 63;
      const int m  = sl & 15, kg = sl >> 4;
      short4v sv = {0, 0, 0, 0};
      if (m < TPB) {
        const float4v hv = *(const float4v*)(h + (size_t)(tok0 + m) * HID + f * 16 + kg * 4);
#pragma unroll
        for (int e = 0; e < 4; ++e) sv[e] = (short)f2bf(hv[e]);
      } else {
        ((short4v*)s_ctxF)[s] = sv;      // zero pad rows once
      }
      ((short4v*)s_hF)[s] = sv;
    }
  }

  // ---- batched q projection for all TPB tokens (transient Bq frags) ----
  {
    short4v Bq[2][8];
    float qb2[2];
#pragma unroll
    for (int nt = 0; nt < 2; ++nt) {
      qb2[nt] = qb[n0 + nt * 16 + lm];
#pragma unroll
      for (int ks = 0; ks < 8; ++ks) {
        short4v bv;
#pragma unroll
        for (int e = 0; e < 4; ++e)
          bv[e] = (short)f2bf(qW[(size_t)(ks * 16 + lg * 4 + e) * HID + n0 + nt * 16 + lm]);
        Bq[nt][ks] = bv;
      }
    }
    __syncthreads();  // s_hF ready
    float4v accq[2];
#pragma unroll
    for (int nt = 0; nt < 2; ++nt) accq[nt] = (float4v){qb2[nt], qb2[nt], qb2[nt], qb2[nt]};
#pragma unroll
    for (int ks = 0; ks < 8; ++ks) {
      const short4v aq = ((const short4v*)s_hF)[ks * 64 + lane];
#pragma unroll
      for (int nt = 0; nt < 2; ++nt)
        accq[nt] = __builtin_amdgcn_mfma_f32_16x16x16bf16_1k(aq, Bq[nt][ks], accq[nt], 0, 0, 0);
    }
#pragma unroll
    for (int nt = 0; nt < 2; ++nt)
#pragma unroll
      for (int r = 0; r < 4; ++r) {
        const int row = lg * 4 + r;                       // token index
        if (row < TPB) s_qall[row * HID + n0 + nt * 16 + lm] = accq[nt][r];
      }
  }

  // ---- persistent k/v weight fragments (registers, loaded once) ----
  short4v Bk[2][8], Bv[2][8];
  float kb2[2], vb2[2];
#pragma unroll
  for (int nt = 0; nt < 2; ++nt) {
    kb2[nt] = kb[n0 + nt * 16 + lm];
    vb2[nt] = vb[n0 + nt * 16 + lm];
#pragma unroll
    for (int ks = 0; ks < 8; ++ks) {
      short4v bk, bv;
#pragma unroll
      for (int e = 0; e < 4; ++e) {
        const size_t widx = (size_t)(ks * 16 + lg * 4 + e) * HID + n0 + nt * 16 + lm;
        bk[e] = (short)f2bf(kW[widx]);
        bv[e] = (short)f2bf(vW[widx]);
      }
      Bk[nt][ks] = bk; Bv[nt][ks] = bv;
    }
  }

  // ---- initial message prefetch (frag-order float4 loads) ----
  float4v P[4];
#pragma unroll
  for (int j = 0; j < 4; ++j) {
    const int f = w + 4 * j, mt = f >> 3, ks = f & 7;
    P[j] = *(const float4v*)(msg + (size_t)tok0 * (NA * HID) + (mt * 16 + lm) * HID + ks * 16 + lg * 4);
  }

  for (int it = 0; it < TPB; ++it) {
    const int tok = tok0 + it;

    // staging: bf16-convert prefetched message -> frag-order LDS (conflict-free b64)
#pragma unroll
    for (int j = 0; j < 4; ++j) {
      const int f = w + 4 * j;
      short4v sv;
#pragma unroll
      for (int e = 0; e < 4; ++e) sv[e] = (short)f2bf(P[j][e]);
      ((short4v*)s_msgF)[f * 64 + lane] = sv;
    }
    __syncthreads();  // B1: msg frags visible (also fences prior-iter s_v/s_p readers)

    // prefetch next token's message under this token's compute
    if (it + 1 < TPB) {
#pragma unroll
      for (int j = 0; j < 4; ++j) {
        const int f = w + 4 * j, mt = f >> 3, ks = f & 7;
        P[j] = *(const float4v*)(msg + (size_t)(tok + 1) * (NA * HID) + (mt * 16 + lm) * HID + ks * 16 + lg * 4);
      }
    }

    // ---- k/v projections via MFMA; store to padded fp32 LDS ----
#pragma unroll
    for (int mt = 0; mt < 2; ++mt) {
      float4v ak[2], av[2];
#pragma unroll
      for (int nt = 0; nt < 2; ++nt) {
        ak[nt] = (float4v){kb2[nt], kb2[nt], kb2[nt], kb2[nt]};
        av[nt] = (float4v){vb2[nt], vb2[nt], vb2[nt], vb2[nt]};
      }
      short4v af[8];
#pragma unroll
      for (int ks = 0; ks < 8; ++ks)
        af[ks] = ((const short4v*)s_msgF)[(mt * 8 + ks) * 64 + lane];
#pragma unroll
      for (int ks = 0; ks < 8; ++ks)
#pragma unroll
        for (int nt = 0; nt < 2; ++nt) {
          ak[nt] = __builtin_amdgcn_mfma_f32_16x16x16bf16_1k(af[ks], Bk[nt][ks], ak[nt], 0, 0, 0);
          av[nt] = __builtin_amdgcn_mfma_f32_16x16x16bf16_1k(af[ks], Bv[nt][ks], av[nt], 0, 0, 0);
        }
#pragma unroll
      for (int nt = 0; nt < 2; ++nt) {
        const int col  = n0 + nt * 16 + lm;
        const int row0 = mt * 16 + lg * 4;
#pragma unroll
        for (int r = 0; r < 4; ++r) {
          s_k[(row0 + r) * KSTR + col] = ak[nt][r];
          s_v[(row0 + r) * KSTR + col] = fmaxf(av[nt][r], 0.f);  // relu
        }
      }
    }
    __syncthreads();  // B2

    // ---- scores + masked softmax: thread (head = t>>5, a = t&31) ----
    {
      const int head = t >> 5, a = t & 31;
      const float4v* qr = (const float4v*)(s_qall + it * HID + head * 16);
      const float4v* kr = (const float4v*)(s_k + a * KSTR + head * 16);
      float sc = 0.f;
#pragma unroll
      for (int dd = 0; dd < 4; ++dd) {
        const float4v q4 = qr[dd], k4 = kr[dd];
#pragma unroll
        for (int e = 0; e < 4; ++e) sc = fmaf(q4[e], k4[e], sc);
      }
      const float m = mask[(size_t)tok * NA + a];
      sc = sc * 0.25f * m;
      if (sc == 0.0f) sc = -1000000.0f;  // exact reference semantics
      float mx = sc;
#pragma unroll
      for (int off = 16; off; off >>= 1) mx = fmaxf(mx, __shfl_xor(mx, off));
      const float e = __expf(sc - mx);
      float sm = e;
#pragma unroll
      for (int off = 16; off; off >>= 1) sm += __shfl_xor(sm, off);
      s_p[head * NA + a] = e / sm * m;   // softmax * mask
    }
    __syncthreads();  // B3

    // ---- PV (t<128): ctx -> bf16 frag slot (row = token) ----
    if (t < HID) {
      const int o = t, head = o >> 4;
      float acc = 0.f;
#pragma unroll
      for (int a = 0; a < NA; ++a)
        acc = fmaf(s_p[head * NA + a], s_v[a * KSTR + o], acc);
      ((unsigned short*)s_ctxF)[(o >> 4) * 256 + ((o & 15) >> 2) * 64 + it * 4 + (o & 3)] = f2bf(acc);
    }
    // no barrier needed: next-iter writes touch only s_msgF (dead after B2); B1 fences s_v/s_p
  }
  __syncthreads();  // ctx frags complete

  // ---- batched d projection (transient Bd frags) ----
  {
    short4v Bd[2][8];
    float db2[2];
#pragma unroll
    for (int nt = 0; nt < 2; ++nt) {
      db2[nt] = db[n0 + nt * 16 + lm];
#pragma unroll
      for (int ks = 0; ks < 8; ++ks) {
        short4v bv;
#pragma unroll
        for (int e = 0; e < 4; ++e)
          bv[e] = (short)f2bf(dW[(size_t)(ks * 16 + lg * 4 + e) * HID + n0 + nt * 16 + lm]);
        Bd[nt][ks] = bv;
      }
    }
    float4v accd[2];
#pragma unroll
    for (int nt = 0; nt < 2; ++nt) accd[nt] = (float4v){db2[nt], db2[nt], db2[nt], db2[nt]};
#pragma unroll
    for (int ks = 0; ks < 8; ++ks) {
      const short4v ad = ((const short4v*)s_ctxF)[ks * 64 + lane];
#pragma unroll
      for (int nt = 0; nt < 2; ++nt)
        accd[nt] = __builtin_amdgcn_mfma_f32_16x16x16bf16_1k(ad, Bd[nt][ks], accd[nt], 0, 0, 0);
    }
#pragma unroll
    for (int nt = 0; nt < 2; ++nt)
#pragma unroll
      for (int r = 0; r < 4; ++r) {
        const int row = lg * 4 + r;                      // token index
        if (row < TPB) s_dall[row * HID + n0 + nt * 16 + lm] = accd[nt][r];
      }
  }
  __syncthreads();

  // ---- residual + layernorm, 32 lanes per token row, float4 ----
  {
    const int row = t >> 5, seg = t & 31;
    const float4v xd = *(const float4v*)(s_dall + row * HID + seg * 4);
    const float4v xh = *(const float4v*)(s_hall + row * HID + seg * 4);
    float x[4];
    float s1 = 0.f, s2 = 0.f;
#pragma unroll
    for (int e = 0; e < 4; ++e) { x[e] = xd[e] + xh[e]; s1 += x[e]; s2 += x[e] * x[e]; }
#pragma unroll
    for (int off = 16; off; off >>= 1) { s1 += __shfl_xor(s1, off); s2 += __shfl_xor(s2, off); }
    const float u   = s1 * (1.f / 128.f);
    const float var = s2 * (1.f / 128.f) - u * u;
    const float rs  = rsqrtf(var + 1e-12f);
    const float4v w4 = *(const float4v*)(lnw + seg * 4);
    const float4v b4 = *(const float4v*)(lnb + seg * 4);
    float4v y;
#pragma unroll
    for (int e = 0; e < 4; ++e) y[e] = w4[e] * ((x[e] - u) * rs) + b4[e];
    *(float4v*)(out + (size_t)(tok0 + row) * HID + seg * 4) = y;
  }
}

extern "C" void kernel_launch(void* const* d_in, const int* in_sizes, int n_in,
                              void* d_out, int out_size, void* d_ws, size_t ws_size,
                              hipStream_t stream) {
  const float* h    = (const float*)d_in[0];
  const float* msg  = (const float*)d_in[1];
  const float* mask = (const float*)d_in[2];
  const float* qW   = (const float*)d_in[3];
  const float* qb   = (const float*)d_in[4];
  const float* kW   = (const float*)d_in[5];
  const float* kb   = (const float*)d_in[6];
  const float* vW   = (const float*)d_in[7];
  const float* vb   = (const float*)d_in[8];
  const float* dW   = (const float*)d_in[9];
  const float* db   = (const float*)d_in[10];
  const float* lnw  = (const float*)d_in[11];
  const float* lnb  = (const float*)d_in[12];
  float* out = (float*)d_out;

  const int n_tokens = in_sizes[0] / HID;          // 16384
  const int nblocks  = n_tokens / TPB;             // 2048 (n_tokens divisible by 8)
  soft_attn_mfma<<<nblocks, 256, 0, stream>>>(
      h, msg, mask, qW, qb, kW, kb, vW, vb, dW, db, lnw, lnb, out, n_tokens);
}